// Round 6
// baseline (1087.593 us; speedup 1.0000x reference)
//
#include <hip/hip_runtime.h>

#define N_NODES 50000
#define N_EDGES 800000
#define N_GRAPHS 512
#define D_IN 128
#define D_EDGE 32
#define D_HID 128
#define D_GLOB 64
#define EGRID 256                    // edge kernel blocks (h slot per block)
#define NTF2 (N_EDGES / 256)         // 3125 fused edge tiles of 256 edges
#define NTP ((N_NODES + 127) / 128)  // 391 node_pre tiles
#define NTN ((N_NODES + 255) / 256)  // 196 node gate/upd tiles

// Static device scratch (zero-init .bss at module load).
__device__ float g_xab[(size_t)N_NODES * 256];    // 51.2 MB: [xa | xb] per node
__device__ float g_agg[(size_t)N_NODES * D_HID];  // 25.6 MB: aggregated messages
__device__ float g_hs[(size_t)EGRID * 256 * 128]; // 33.5 MB: per-block h slots
__device__ float g_pooled[N_GRAPHS * D_HID];      // 256 KB: per-graph pooled sums
__device__ int g_counts[N_NODES];
__device__ int g_cursor[N_NODES];
__device__ int g_perm[N_EDGES];

__device__ __forceinline__ int clampi(int v, int hi) {   // [0, hi)
    return v < 0 ? 0 : (v >= hi ? hi - 1 : v);
}

// ---------------------------------------------------------------------------
// Zero scratch that must be fresh every launch.
// ---------------------------------------------------------------------------
__global__ void zero_aux_kernel()
{
    const size_t i = (size_t)blockIdx.x * 256 + threadIdx.x;
    const float4 z = make_float4(0.f, 0.f, 0.f, 0.f);
    if (i < (size_t)N_NODES * 32) ((float4*)g_agg)[i] = z;
    if (i < N_GRAPHS * 32)        ((float4*)g_pooled)[i] = z;
    if (i < N_NODES)              g_counts[i] = 0;
}

// ---------------------------------------------------------------------------
// Counting-sort of edges by destination node.
// ---------------------------------------------------------------------------
__global__ void hist_kernel(const int* __restrict__ eidx)
{
    int e = blockIdx.x * 256 + threadIdx.x;
    if (e < N_EDGES) atomicAdd(&g_counts[clampi(eidx[N_EDGES + e], N_NODES)], 1);
}

#define SCAN_HALF 25088   // 256 * 98
#define SCAN_CH 98
__global__ __launch_bounds__(512) void scan_kernel()
{
    __shared__ int buf[SCAN_HALF];
    __shared__ int part[512];
    const int t = threadIdx.x;

    #pragma unroll 1
    for (int p = 0; p < 2; ++p) {
        const int base = p * SCAN_HALF;
        __syncthreads();
        for (int i = t; i < SCAN_HALF; i += 512) {
            int gg = base + i;
            buf[i] = (gg < N_NODES) ? g_counts[gg] : 0;
        }
        __syncthreads();
        if ((t >> 8) == p) {
            const int l0 = t * SCAN_CH - base;
            int s = 0;
            for (int i = 0; i < SCAN_CH; ++i) s += buf[l0 + i];
            part[t] = s;
        }
    }
    __syncthreads();
    if (t == 0) {
        int run = 0;
        for (int i = 0; i < 512; ++i) { int v = part[i]; part[i] = run; run += v; }
    }
    #pragma unroll 1
    for (int p = 0; p < 2; ++p) {
        const int base = p * SCAN_HALF;
        __syncthreads();
        for (int i = t; i < SCAN_HALF; i += 512) {
            int gg = base + i;
            buf[i] = (gg < N_NODES) ? g_counts[gg] : 0;
        }
        __syncthreads();
        if ((t >> 8) == p) {
            const int l0 = t * SCAN_CH - base;
            int run = part[t];
            for (int i = 0; i < SCAN_CH; ++i) { int v = buf[l0 + i]; buf[l0 + i] = run; run += v; }
        }
        __syncthreads();
        for (int i = t; i < SCAN_HALF; i += 512) {
            int gg = base + i;
            if (gg < N_NODES) g_cursor[gg] = buf[i];
        }
    }
}

__global__ void scatter_kernel(const int* __restrict__ eidx)
{
    int e = blockIdx.x * 256 + threadIdx.x;
    if (e < N_EDGES) {
        int d = clampi(eidx[N_EDGES + e], N_NODES);
        int p = atomicAdd(&g_cursor[d], 1);
        g_perm[p] = e;
    }
}

// ---------------------------------------------------------------------------
// Register-tile GEMM core (R rows x 8 cols per thread). A streams from
// global/LDS into double-buffered registers; W is LDS-resident with leading
// dim LD and second-column-group offset OFF. Conflict-free b128 reads.
// ---------------------------------------------------------------------------
template<int R, int KBASE, int LD, int OFF>
__device__ __forceinline__ void step4(const float* __restrict__ sW, int kg, int tx,
                                      const float4 (&a)[R], float (&acc)[R][8])
{
    #pragma unroll
    for (int kk = 0; kk < 4; ++kk) {
        const float* wr = sW + (size_t)(KBASE + kg * 4 + kk) * LD + tx * 4;
        float4 w0 = *(const float4*)(wr);
        float4 w1 = *(const float4*)(wr + OFF);
        #pragma unroll
        for (int r = 0; r < R; ++r) {
            const float av = ((const float*)&a[r])[kk];
            acc[r][0] = fmaf(av, w0.x, acc[r][0]);
            acc[r][1] = fmaf(av, w0.y, acc[r][1]);
            acc[r][2] = fmaf(av, w0.z, acc[r][2]);
            acc[r][3] = fmaf(av, w0.w, acc[r][3]);
            acc[r][4] = fmaf(av, w1.x, acc[r][4]);
            acc[r][5] = fmaf(av, w1.y, acc[r][5]);
            acc[r][6] = fmaf(av, w1.z, acc[r][6]);
            acc[r][7] = fmaf(av, w1.w, acc[r][7]);
        }
    }
}

template<int R, int KBASE, int KG, int LD, int OFF>
__device__ __forceinline__ void gemm_seg(const float* __restrict__ sW, int tx,
                                         const float* const (&bp)[R],
                                         float (&acc)[R][8])
{
    float4 a0[R], a1[R];
    #pragma unroll
    for (int r = 0; r < R; ++r) a0[r] = *(const float4*)(bp[r]);
    #pragma unroll 1
    for (int kg = 0; kg < KG; kg += 2) {
        #pragma unroll
        for (int r = 0; r < R; ++r) a1[r] = *(const float4*)(bp[r] + (kg + 1) * 4);
        step4<R, KBASE, LD, OFF>(sW, kg, tx, a0, acc);
        if (kg + 2 < KG) {
            #pragma unroll
            for (int r = 0; r < R; ++r) a0[r] = *(const float4*)(bp[r] + (kg + 2) * 4);
        }
        step4<R, KBASE, LD, OFF>(sW, kg + 1, tx, a1, acc);
    }
}

// ---------------------------------------------------------------------------
// Node precompute: xab[n] = x[n] @ [We1_top | We1_bot]  (unchanged, proven)
// ---------------------------------------------------------------------------
__global__ __launch_bounds__(512, 2) void node_pre_kernel(
    const float* __restrict__ x, const float* __restrict__ We1)
{
    __shared__ float sWp[128 * 256];     // 131072 B
    const int tid = threadIdx.x;
    const int tx = tid & 31;
    const int ty = tid >> 5;

    #pragma unroll 4
    for (int it = 0; it < 16; ++it) {
        int idx = it * 512 + tid;
        int k = idx >> 6;
        int c = (idx & 63) * 4;
        const float* src = (c < 128) ? (We1 + (size_t)k * 128 + c)
                                     : (We1 + (size_t)(128 + k) * 128 + (c - 128));
        *(float4*)&sWp[(size_t)idx * 4] = *(const float4*)src;
    }
    __syncthreads();

    for (int t = blockIdx.x; t < NTP; t += gridDim.x) {
        const int n0 = t * 128;
        float acc[8][8];
        #pragma unroll
        for (int r = 0; r < 8; ++r)
            #pragma unroll
            for (int c = 0; c < 8; ++c) acc[r][c] = 0.f;

        const float* bp[8];
        #pragma unroll
        for (int r = 0; r < 8; ++r) {
            int n = n0 + ty * 8 + r;
            if (n >= N_NODES) n = N_NODES - 1;
            bp[r] = x + (size_t)n * 128;
        }
        gemm_seg<8, 0, 32, 256, 128>(sWp, tx, bp, acc);

        #pragma unroll
        for (int r = 0; r < 8; ++r) {
            int n = n0 + ty * 8 + r;
            if (n < N_NODES) {
                float* dst = g_xab + (size_t)n * 256;
                *(float4*)(dst + tx * 4)       = make_float4(acc[r][0], acc[r][1], acc[r][2], acc[r][3]);
                *(float4*)(dst + 128 + tx * 4) = make_float4(acc[r][4], acc[r][5], acc[r][6], acc[r][7]);
            }
        }
    }
}

// ---------------------------------------------------------------------------
// Fused edge kernel v2: 256-edge tiles, 512 threads, R=8 both phases.
//  ph1: h = relu(xa[src]+xb[dst] + attr@W1c + be1) in regs -> store to this
//       block's global h slot (L1/L2-hot; same-CU producer/consumer).
//  barrier (drains stores)
//  ph2: msg GEMM vs LDS-resident We2 (K=128); A streams from h slot via VMEM
//       (keeps the LDS pipe weight-only: 8 b128/kg for 256 FMA -> VALU-bound).
//  ph3/4: r4-proven 2x128-row staging + run-segmented reduce -> g_agg;
//       atomics only at boundary runs.
// LDS: 16K(W1c)+64K(We2)+67.6K(sRed)+~4K = ~152 KB -> 1 block/CU, 8 waves.
// ---------------------------------------------------------------------------
__global__ __launch_bounds__(512, 2) void edge_fused2_kernel(
    const int* __restrict__ eidx, const float* __restrict__ eattr,
    const float* __restrict__ We1, const float* __restrict__ be1,
    const float* __restrict__ We2, const float* __restrict__ be2)
{
    __shared__ float sWc[32 * 128];      // 16384 B: We1 rows 256..288
    __shared__ float sW2[128 * 128];     // 65536 B
    __shared__ float sRed[128][132];     // 67584 B
    __shared__ int sSrc[256], sDst[256], sEdg[256];
    __shared__ int sRunS[2][130];
    __shared__ int sNR[2], sAF[2], sAL[2];

    const int tid = threadIdx.x;
    const int tx = tid & 15;
    const int ty = tid >> 4;             // [0,32), 8 rows each
    const int wid = tid >> 6;
    const int lane = tid & 63;

    float* hslot = g_hs + (size_t)blockIdx.x * 256 * 128;

    #pragma unroll
    for (int it = 0; it < 2; ++it)
        ((float4*)sWc)[it * 512 + tid] = ((const float4*)(We1 + (size_t)256 * 128))[it * 512 + tid];
    #pragma unroll 4
    for (int it = 0; it < 8; ++it)
        ((float4*)sW2)[it * 512 + tid] = ((const float4*)We2)[it * 512 + tid];

    const float4 b0 = *(const float4*)&be1[tx * 4];
    const float4 b1 = *(const float4*)&be1[64 + tx * 4];
    const float4 c0 = *(const float4*)&be2[tx * 4];
    const float4 c1 = *(const float4*)&be2[64 + tx * 4];

    for (int t = blockIdx.x; t < NTF2; t += gridDim.x) {
        const int e0 = t * 256;
        __syncthreads();                 // weights ready / prior tile done
        if (tid < 256) {
            int p = g_perm[e0 + tid];
            sEdg[tid] = p;
            sSrc[tid] = clampi(eidx[p], N_NODES);
            sDst[tid] = clampi(eidx[N_EDGES + p], N_NODES);
        }
        __syncthreads();

        // run detection (2 lanes; overlaps with phase 1 on other waves)
        if (tid < 2) {
            const int base = tid * 128;
            int prev = (base == 0)
                ? ((e0 > 0) ? clampi(eidx[N_EDGES + g_perm[e0 - 1]], N_NODES) : -1)
                : sDst[base - 1];
            sAF[tid] = (prev == sDst[base]) ? 1 : 0;
            int n = 0;
            for (int i = 0; i < 128; ++i) {
                int d = sDst[base + i];
                if (i == 0 || d != sDst[base + i - 1]) sRunS[tid][n++] = base + i;
            }
            sRunS[tid][n] = base + 128;
            sNR[tid] = n;
            int nxt = (base == 128)
                ? ((e0 + 256 < N_EDGES) ? clampi(eidx[N_EDGES + g_perm[e0 + 256]], N_NODES) : -1)
                : sDst[128];
            sAL[tid] = (nxt == sDst[base + 127]) ? 1 : 0;
        }

        // ---- phase 1: h rows = xa[src] + xb[dst] + attr@W1c (R=8) ----
        float acc[8][8];
        #pragma unroll
        for (int rp = 0; rp < 4; ++rp) {
            float4 xa0[2], xa1[2], xb0[2], xb1[2];
            #pragma unroll
            for (int i = 0; i < 2; ++i) {
                const int row = ty * 8 + rp * 2 + i;
                const float* pa = g_xab + (size_t)sSrc[row] * 256 + tx * 4;
                const float* pb = g_xab + (size_t)sDst[row] * 256 + 128 + tx * 4;
                xa0[i] = *(const float4*)(pa);
                xa1[i] = *(const float4*)(pa + 64);
                xb0[i] = *(const float4*)(pb);
                xb1[i] = *(const float4*)(pb + 64);
            }
            #pragma unroll
            for (int i = 0; i < 2; ++i) {
                const int r = rp * 2 + i;
                acc[r][0] = xa0[i].x + xb0[i].x; acc[r][1] = xa0[i].y + xb0[i].y;
                acc[r][2] = xa0[i].z + xb0[i].z; acc[r][3] = xa0[i].w + xb0[i].w;
                acc[r][4] = xa1[i].x + xb1[i].x; acc[r][5] = xa1[i].y + xb1[i].y;
                acc[r][6] = xa1[i].z + xb1[i].z; acc[r][7] = xa1[i].w + xb1[i].w;
            }
        }
        #pragma unroll 1
        for (int kg = 0; kg < 8; ++kg) {
            float4 av[8];
            #pragma unroll
            for (int r = 0; r < 8; ++r)
                av[r] = *(const float4*)(eattr + (size_t)sEdg[ty * 8 + r] * 32 + kg * 4);
            #pragma unroll
            for (int kk = 0; kk < 4; ++kk) {
                const float* wr = sWc + (size_t)(kg * 4 + kk) * 128 + tx * 4;
                float4 w0 = *(const float4*)(wr);
                float4 w1 = *(const float4*)(wr + 64);
                #pragma unroll
                for (int r = 0; r < 8; ++r) {
                    const float a = ((const float*)&av[r])[kk];
                    acc[r][0] = fmaf(a, w0.x, acc[r][0]);
                    acc[r][1] = fmaf(a, w0.y, acc[r][1]);
                    acc[r][2] = fmaf(a, w0.z, acc[r][2]);
                    acc[r][3] = fmaf(a, w0.w, acc[r][3]);
                    acc[r][4] = fmaf(a, w1.x, acc[r][4]);
                    acc[r][5] = fmaf(a, w1.y, acc[r][5]);
                    acc[r][6] = fmaf(a, w1.z, acc[r][6]);
                    acc[r][7] = fmaf(a, w1.w, acc[r][7]);
                }
            }
        }
        // bias + relu -> h slot (global, this CU's L1/L2)
        #pragma unroll
        for (int r = 0; r < 8; ++r) {
            float* dst = hslot + (size_t)(ty * 8 + r) * 128 + tx * 4;
            float4 v;
            v.x = fmaxf(acc[r][0] + b0.x, 0.f); v.y = fmaxf(acc[r][1] + b0.y, 0.f);
            v.z = fmaxf(acc[r][2] + b0.z, 0.f); v.w = fmaxf(acc[r][3] + b0.w, 0.f);
            *(float4*)(dst) = v;
            v.x = fmaxf(acc[r][4] + b1.x, 0.f); v.y = fmaxf(acc[r][5] + b1.y, 0.f);
            v.z = fmaxf(acc[r][6] + b1.z, 0.f); v.w = fmaxf(acc[r][7] + b1.w, 0.f);
            *(float4*)(dst + 64) = v;
        }
        __syncthreads();                 // drain h stores (vmcnt(0) at barrier)

        // ---- phase 2: msg GEMM, A from h slot (VMEM), W from LDS ----
        float acc2[8][8];
        #pragma unroll
        for (int r = 0; r < 8; ++r)
            #pragma unroll
            for (int c = 0; c < 8; ++c) acc2[r][c] = 0.f;
        {
            const float* bp[8];
            #pragma unroll
            for (int r = 0; r < 8; ++r) bp[r] = hslot + (size_t)(ty * 8 + r) * 128;
            gemm_seg<8, 0, 32, 128, 64>(sW2, tx, bp, acc2);
        }

        // ---- phase 3/4: stage 128-row groups, run-segmented reduce ----
        #pragma unroll 1
        for (int g2 = 0; g2 < 2; ++g2) {
            __syncthreads();             // prior group reads done / runs ready
            if ((ty >> 4) == g2) {
                const int lr = (ty & 15) * 8;
                #pragma unroll
                for (int r = 0; r < 8; ++r) {
                    float4 v;
                    v.x = fmaxf(acc2[r][0] + c0.x, 0.f); v.y = fmaxf(acc2[r][1] + c0.y, 0.f);
                    v.z = fmaxf(acc2[r][2] + c0.z, 0.f); v.w = fmaxf(acc2[r][3] + c0.w, 0.f);
                    *(float4*)&sRed[lr + r][ 0 + tx * 4] = v;
                    v.x = fmaxf(acc2[r][4] + c1.x, 0.f); v.y = fmaxf(acc2[r][5] + c1.y, 0.f);
                    v.z = fmaxf(acc2[r][6] + c1.z, 0.f); v.w = fmaxf(acc2[r][7] + c1.w, 0.f);
                    *(float4*)&sRed[lr + r][64 + tx * 4] = v;
                }
            }
            __syncthreads();
            const int nR = sNR[g2];
            for (int m = wid; m < nR; m += 8) {      // one wave per run
                const int s = sRunS[g2][m]     - g2 * 128;
                const int e = sRunS[g2][m + 1] - g2 * 128;
                float v0 = 0.f, v1 = 0.f;
                for (int r = s; r < e; ++r) { v0 += sRed[r][lane]; v1 += sRed[r][64 + lane - 64 + 64]; }
                // (second term reads cols 64..127)
                v1 = 0.f;
                for (int r = s; r < e; ++r) v1 += sRed[r][64 + lane];
                const int d = sDst[g2 * 128 + s];
                float* dst = g_agg + (size_t)d * 128;
                const bool atom = (m == 0 && sAF[g2]) || (m == nR - 1 && sAL[g2]);
                if (atom) {
                    unsafeAtomicAdd(dst + lane,      v0);
                    unsafeAtomicAdd(dst + lane + 64, v1);
                } else {
                    dst[lane]      = v0;             // exclusive owner
                    dst[lane + 64] = v1;
                }
            }
        }
    }
}

// ---------------------------------------------------------------------------
// Node gate: x_weights[n] = sigmoid([x[n]|agg[n]] @ Wg + bg).  (unchanged)
// ---------------------------------------------------------------------------
__global__ __launch_bounds__(512, 2) void node_gate_kernel(
    const float* __restrict__ x, const float* __restrict__ Wg,
    const float* __restrict__ bg, float* __restrict__ xw_out)
{
    __shared__ float sW[256 * 128];      // 131072 B
    const int tid = threadIdx.x;
    const int tx = tid & 15;
    const int ty = tid >> 4;

    #pragma unroll 4
    for (int it = 0; it < 16; ++it)
        ((float4*)sW)[it * 512 + tid] = ((const float4*)Wg)[it * 512 + tid];
    __syncthreads();

    const float4 b0 = *(const float4*)&bg[tx * 4];
    const float4 b1 = *(const float4*)&bg[64 + tx * 4];
    const int n0 = blockIdx.x * 256;

    float acc[8][8];
    #pragma unroll
    for (int r = 0; r < 8; ++r)
        #pragma unroll
        for (int c = 0; c < 8; ++c) acc[r][c] = 0.f;

    const float* bp[8];
    #pragma unroll
    for (int r = 0; r < 8; ++r) {
        int n = n0 + ty * 8 + r; if (n >= N_NODES) n = N_NODES - 1;
        bp[r] = x + (size_t)n * 128;
    }
    gemm_seg<8, 0, 32, 128, 64>(sW, tx, bp, acc);
    #pragma unroll
    for (int r = 0; r < 8; ++r) {
        int n = n0 + ty * 8 + r; if (n >= N_NODES) n = N_NODES - 1;
        bp[r] = g_agg + (size_t)n * 128;
    }
    gemm_seg<8, 128, 32, 128, 64>(sW, tx, bp, acc);

    #pragma unroll
    for (int r = 0; r < 8; ++r) {
        const int n = n0 + ty * 8 + r;
        if (n < N_NODES) {
            float4 v;
            v.x = 1.f / (1.f + __expf(-(acc[r][0] + b0.x)));
            v.y = 1.f / (1.f + __expf(-(acc[r][1] + b0.y)));
            v.z = 1.f / (1.f + __expf(-(acc[r][2] + b0.z)));
            v.w = 1.f / (1.f + __expf(-(acc[r][3] + b0.w)));
            *(float4*)&xw_out[(size_t)n * 128 + tx * 4] = v;
            v.x = 1.f / (1.f + __expf(-(acc[r][4] + b1.x)));
            v.y = 1.f / (1.f + __expf(-(acc[r][5] + b1.y)));
            v.z = 1.f / (1.f + __expf(-(acc[r][6] + b1.z)));
            v.w = 1.f / (1.f + __expf(-(acc[r][7] + b1.w)));
            *(float4*)&xw_out[(size_t)n * 128 + 64 + tx * 4] = v;
        }
    }
}

// ---------------------------------------------------------------------------
// Node update: x_new = gate * relu([x|agg] @ Wn + bn); pooled via run-
// segmented scalar atomics.  (unchanged)
// ---------------------------------------------------------------------------
__global__ __launch_bounds__(512, 2) void node_upd_kernel(
    const float* __restrict__ x, const int* __restrict__ batch,
    const float* __restrict__ Wn, const float* __restrict__ bn,
    const float* __restrict__ xw_out)
{
    __shared__ float sW[256 * 128];      // 131072 B
    __shared__ int sB[256];
    const int tid = threadIdx.x;
    const int tx = tid & 15;
    const int ty = tid >> 4;
    const int n0 = blockIdx.x * 256;

    #pragma unroll 4
    for (int it = 0; it < 16; ++it)
        ((float4*)sW)[it * 512 + tid] = ((const float4*)Wn)[it * 512 + tid];
    if (tid < 256) {
        int n = n0 + tid;
        sB[tid] = (n < N_NODES) ? batch[n] : -2;
    }
    __syncthreads();

    const float4 b0 = *(const float4*)&bn[tx * 4];
    const float4 b1 = *(const float4*)&bn[64 + tx * 4];

    float acc[8][8];
    #pragma unroll
    for (int r = 0; r < 8; ++r)
        #pragma unroll
        for (int c = 0; c < 8; ++c) acc[r][c] = 0.f;

    const float* bp[8];
    #pragma unroll
    for (int r = 0; r < 8; ++r) {
        int n = n0 + ty * 8 + r; if (n >= N_NODES) n = N_NODES - 1;
        bp[r] = x + (size_t)n * 128;
    }
    gemm_seg<8, 0, 32, 128, 64>(sW, tx, bp, acc);
    #pragma unroll
    for (int r = 0; r < 8; ++r) {
        int n = n0 + ty * 8 + r; if (n >= N_NODES) n = N_NODES - 1;
        bp[r] = g_agg + (size_t)n * 128;
    }
    gemm_seg<8, 128, 32, 128, 64>(sW, tx, bp, acc);

    float ps[8];
    int cg = -1;
    #pragma unroll
    for (int r = 0; r < 8; ++r) {
        const int n = n0 + ty * 8 + r;
        if (n < N_NODES) {
            const float4 ga = *(const float4*)&xw_out[(size_t)n * 128 + tx * 4];
            const float4 gb = *(const float4*)&xw_out[(size_t)n * 128 + 64 + tx * 4];
            float v[8];
            v[0] = ga.x * fmaxf(acc[r][0] + b0.x, 0.f);
            v[1] = ga.y * fmaxf(acc[r][1] + b0.y, 0.f);
            v[2] = ga.z * fmaxf(acc[r][2] + b0.z, 0.f);
            v[3] = ga.w * fmaxf(acc[r][3] + b0.w, 0.f);
            v[4] = gb.x * fmaxf(acc[r][4] + b1.x, 0.f);
            v[5] = gb.y * fmaxf(acc[r][5] + b1.y, 0.f);
            v[6] = gb.z * fmaxf(acc[r][6] + b1.z, 0.f);
            v[7] = gb.w * fmaxf(acc[r][7] + b1.w, 0.f);
            const int gph = sB[ty * 8 + r];
            if (gph != cg) {
                if (cg >= 0) {
                    #pragma unroll
                    for (int j = 0; j < 4; ++j)
                        unsafeAtomicAdd(&g_pooled[(size_t)cg * 128 + tx * 4 + j], ps[j]);
                    #pragma unroll
                    for (int j = 0; j < 4; ++j)
                        unsafeAtomicAdd(&g_pooled[(size_t)cg * 128 + 64 + tx * 4 + j], ps[4 + j]);
                }
                cg = gph;
                #pragma unroll
                for (int j = 0; j < 8; ++j) ps[j] = v[j];
            } else {
                #pragma unroll
                for (int j = 0; j < 8; ++j) ps[j] += v[j];
            }
        }
    }
    if (cg >= 0) {
        #pragma unroll
        for (int j = 0; j < 4; ++j)
            unsafeAtomicAdd(&g_pooled[(size_t)cg * 128 + tx * 4 + j], ps[j]);
        #pragma unroll
        for (int j = 0; j < 4; ++j)
            unsafeAtomicAdd(&g_pooled[(size_t)cg * 128 + 64 + tx * 4 + j], ps[4 + j]);
    }
}

// ---------------------------------------------------------------------------
// Global block: u_new[g] = relu([u[g] | pooled[g]/cnt] @ Wu + bu). (unchanged)
// ---------------------------------------------------------------------------
__global__ __launch_bounds__(64) void global_kernel(
    const int* __restrict__ batch, const float* __restrict__ u,
    const float* __restrict__ Wu, const float* __restrict__ bu,
    float* __restrict__ out)
{
    __shared__ float cat[192];
    __shared__ int sRange[2];
    const int g = blockIdx.x;
    const int t = threadIdx.x;

    if (t == 0) {
        int lo = 0, hi = N_NODES;
        while (lo < hi) { int m = (lo + hi) >> 1; if (batch[m] < g) lo = m + 1; else hi = m; }
        sRange[0] = lo;
        hi = N_NODES;
        while (lo < hi) { int m = (lo + hi) >> 1; if (batch[m] < g + 1) lo = m + 1; else hi = m; }
        sRange[1] = lo;
    }
    __syncthreads();
    const float cnt = fmaxf((float)(sRange[1] - sRange[0]), 1.0f);

    cat[t] = u[g * 64 + t];
    #pragma unroll
    for (int i = 0; i < 2; ++i)
        cat[64 + i * 64 + t] = g_pooled[g * 128 + i * 64 + t] / cnt;
    __syncthreads();

    float acc = bu[t];
    #pragma unroll 4
    for (int k = 0; k < 192; ++k)
        acc = fmaf(cat[k], Wu[k * 64 + t], acc);
    out[g * 64 + t] = fmaxf(acc, 0.f);
}

// ---------------------------------------------------------------------------
extern "C" void kernel_launch(void* const* d_in, const int* in_sizes, int n_in,
                              void* d_out, int out_size, void* d_ws, size_t ws_size,
                              hipStream_t stream) {
    const float* x     = (const float*)d_in[0];
    const int*   eidx  = (const int*)d_in[1];
    const float* eattr = (const float*)d_in[2];
    const float* u     = (const float*)d_in[3];
    const int*   batch = (const int*)d_in[4];
    const float* We1   = (const float*)d_in[5];
    const float* be1   = (const float*)d_in[6];
    const float* We2   = (const float*)d_in[7];
    const float* be2   = (const float*)d_in[8];
    const float* Wg    = (const float*)d_in[9];
    const float* bg    = (const float*)d_in[10];
    const float* Wn    = (const float*)d_in[11];
    const float* bn    = (const float*)d_in[12];
    const float* Wu    = (const float*)d_in[13];
    const float* bu    = (const float*)d_in[14];

    float* out    = (float*)d_out;                 // chunk 0: u_new [512*64] fp32
    float* xw_out = out + N_GRAPHS * D_GLOB;       // chunk 1: x_weights [50000*128] fp32

    zero_aux_kernel<<<6250, 256, 0, stream>>>();
    hist_kernel<<<(N_EDGES + 255) / 256, 256, 0, stream>>>(eidx);
    scan_kernel<<<1, 512, 0, stream>>>();
    scatter_kernel<<<(N_EDGES + 255) / 256, 256, 0, stream>>>(eidx);
    node_pre_kernel<<<196, 512, 0, stream>>>(x, We1);
    edge_fused2_kernel<<<EGRID, 512, 0, stream>>>(eidx, eattr, We1, be1, We2, be2);
    node_gate_kernel<<<NTN, 512, 0, stream>>>(x, Wg, bg, xw_out);
    node_upd_kernel<<<NTN, 512, 0, stream>>>(x, batch, Wn, bn, xw_out);
    global_kernel<<<N_GRAPHS, 64, 0, stream>>>(batch, u, Wu, bu, out);
}